// Round 2
// baseline (6634.071 us; speedup 1.0000x reference)
//
#include <hip/hip_runtime.h>
#include <hip/hip_bf16.h>

#define Bsz 256
#define Tt  512
#define Hh  128

// ws layout (floats):
//   Wt_ih [3][128][512]   k-major transposed input weights (layer0: only k<8 valid)
//   Wt_hh [3][128][512]   k-major transposed recurrent weights
//   bias  [3][512]        bih + bhh
//   hbuf  [2][3][256][128] double-buffered hidden states
//   cbuf  [3][256][128]    cell states (in-place)
#define OFF_WTHH 196608            // 3*128*512
#define OFF_BIAS 393216            // 2*196608
#define OFF_HBUF 394752            // + 3*512
#define OFF_CBUF 591360            // + 2*3*256*128
// total 689664 floats = 2.76 MB

__global__ void prep_kernel(const float* Wih0, const float* Whh0, const float* bih0, const float* bhh0,
                            const float* Wih1, const float* Whh1, const float* bih1, const float* bhh1,
                            const float* Wih2, const float* Whh2, const float* bih2, const float* bhh2,
                            float* ws)
{
    int gid = blockIdx.x * blockDim.x + threadIdx.x;   // 0..1535
    if (gid >= 3 * 512) return;
    int l = gid >> 9, gc = gid & 511;
    const float* Wih = (l == 0) ? Wih0 : (l == 1) ? Wih1 : Wih2;
    const float* Whh = (l == 0) ? Whh0 : (l == 1) ? Whh1 : Whh2;
    const float* bih = (l == 0) ? bih0 : (l == 1) ? bih1 : bih2;
    const float* bhh = (l == 0) ? bhh0 : (l == 1) ? bhh1 : bhh2;
    int Kin = (l == 0) ? 8 : 128;
    float* Wt_ih = ws + (size_t)l * 128 * 512;
    float* Wt_hh = ws + OFF_WTHH + (size_t)l * 128 * 512;
    float* bias  = ws + OFF_BIAS + l * 512;
    for (int k = 0; k < Kin; k++) Wt_ih[k * 512 + gc] = Wih[gc * Kin + k];
    for (int k = 0; k < 128; k++) Wt_hh[k * 512 + gc] = Whh[gc * 128 + k];
    bias[gc] = bih[gc] + bhh[gc];
}

// grid = 192 blocks: layer = blockIdx/64 processes t = s - layer (wavefront).
// Per layer: 64 tiles = 16 row-tiles(16 rows) x 4 hcol-tiles(32 hcols).
// Each block computes all 4 gates for its hcols -> cell update is block-local.
__global__ __launch_bounds__(256) void step_kernel(const float* __restrict__ x,
                                                   float* __restrict__ ws, int s)
{
    const float* Wt_ih = ws;
    const float* Wt_hh = ws + OFF_WTHH;
    const float* bias  = ws + OFF_BIAS;
    float* hbuf = ws + OFF_HBUF;
    float* cbuf = ws + OFF_CBUF;

    int layer = blockIdx.x >> 6;
    int t = s - layer;
    if (t < 0 || t >= Tt) return;
    int tile = blockIdx.x & 63;
    int r0  = (tile & 15) << 4;   // batch rows [r0, r0+16)
    int hc0 = (tile >> 4) << 5;   // hidden cols [hc0, hc0+32)
    int tid = threadIdx.x;

    __shared__ float sAin[16][132];
    __shared__ float sArec[16][132];
    __shared__ float sG[16][132];

    int prev = (s - 1) & 1, cur = s & 1;
    const float* hprev_rec = hbuf + ((size_t)prev * 3 + layer) * Bsz * Hh;

    // ---- stage A tiles into LDS ----
    if (layer == 0) {
        if (tid < 128) {
            int r = tid >> 3, i = tid & 7;
            sAin[r][i] = x[((size_t)(r0 + r) * Tt + t) * 8 + i];
        }
    } else {
        const float* hprev_in = hbuf + ((size_t)prev * 3 + (layer - 1)) * Bsz * Hh;
        int e = tid * 8; int r = e >> 7, k = e & 127;
        const float* src = hprev_in + (size_t)(r0 + r) * Hh + k;
        *(float4*)&sAin[r][k]     = *(const float4*)(src);
        *(float4*)&sAin[r][k + 4] = *(const float4*)(src + 4);
    }
    if (t > 0) {
        int e = tid * 8; int r = e >> 7, k = e & 127;
        const float* src = hprev_rec + (size_t)(r0 + r) * Hh + k;
        *(float4*)&sArec[r][k]     = *(const float4*)(src);
        *(float4*)&sArec[r][k + 4] = *(const float4*)(src + 4);
    }
    __syncthreads();

    // ---- GEMM: each thread: 8 rows x 1 gate-col ----
    int c  = tid & 127;           // 0..127 -> gate g=c>>5, within-gate col
    int rg = tid >> 7;            // 0/1 -> rows rg*8 .. rg*8+7
    int gc = ((c >> 5) << 7) + hc0 + (c & 31);   // actual gate column 0..511
    float bb = bias[layer * 512 + gc];
    float acc[8];
#pragma unroll
    for (int j = 0; j < 8; j++) acc[j] = bb;

    {   // input contribution
        int Kin = (layer == 0) ? 8 : 128;
        const float* W = Wt_ih + (size_t)layer * 128 * 512 + gc;
        for (int k = 0; k < Kin; k += 4) {
            float w0 = W[(k + 0) * 512], w1 = W[(k + 1) * 512];
            float w2 = W[(k + 2) * 512], w3 = W[(k + 3) * 512];
#pragma unroll
            for (int j = 0; j < 8; j++) {
                float4 a = *(const float4*)&sAin[rg * 8 + j][k];
                acc[j] += a.x * w0 + a.y * w1 + a.z * w2 + a.w * w3;
            }
        }
    }
    if (t > 0) {  // recurrent contribution
        const float* W = Wt_hh + (size_t)layer * 128 * 512 + gc;
        for (int k = 0; k < 128; k += 4) {
            float w0 = W[(k + 0) * 512], w1 = W[(k + 1) * 512];
            float w2 = W[(k + 2) * 512], w3 = W[(k + 3) * 512];
#pragma unroll
            for (int j = 0; j < 8; j++) {
                float4 a = *(const float4*)&sArec[rg * 8 + j][k];
                acc[j] += a.x * w0 + a.y * w1 + a.z * w2 + a.w * w3;
            }
        }
    }
#pragma unroll
    for (int j = 0; j < 8; j++) sG[rg * 8 + j][c] = acc[j];
    __syncthreads();

    // ---- LSTM cell update: 512 cells / block, 2 per thread ----
    float* hcur = hbuf + ((size_t)cur * 3 + layer) * Bsz * Hh;
    float* cl   = cbuf + (size_t)layer * Bsz * Hh;
#pragma unroll
    for (int u = 0; u < 2; ++u) {
        int idx = tid + u * 256;
        int r = idx >> 5, wc = idx & 31;
        float gi = sG[r][wc],      gf = sG[r][32 + wc];
        float gg = sG[r][64 + wc], go = sG[r][96 + wc];
        size_t off = (size_t)(r0 + r) * Hh + hc0 + wc;
        float cp = (t > 0) ? cl[off] : 0.f;
        float si = 1.f / (1.f + __expf(-gi));
        float sf = 1.f / (1.f + __expf(-gf));
        float so = 1.f / (1.f + __expf(-go));
        float cn = sf * cp + si * tanhf(gg);
        cl[off]   = cn;
        hcur[off] = so * tanhf(cn);
    }
}

__global__ void fc_kernel(const float* __restrict__ ws, const float* __restrict__ Wfc,
                          const float* __restrict__ bfc, float* __restrict__ out)
{
    // final h of layer2 written at s=513 -> hbuf[1][2]
    const float* h2 = ws + OFF_HBUF + (size_t)(1 * 3 + 2) * Bsz * Hh;
    int b = threadIdx.x;   // 256 threads
    float a0 = bfc[0], a1 = bfc[1], a2 = bfc[2];
    for (int k = 0; k < 128; k++) {
        float h = h2[b * 128 + k];
        a0 += h * Wfc[0 * 128 + k];
        a1 += h * Wfc[1 * 128 + k];
        a2 += h * Wfc[2 * 128 + k];
    }
    out[b * 3 + 0] = a0;
    out[b * 3 + 1] = a1;
    out[b * 3 + 2] = a2;
}

extern "C" void kernel_launch(void* const* d_in, const int* in_sizes, int n_in,
                              void* d_out, int out_size, void* d_ws, size_t ws_size,
                              hipStream_t stream)
{
    const float* x = (const float*)d_in[0];
    float* ws = (float*)d_ws;

    prep_kernel<<<6, 256, 0, stream>>>(
        (const float*)d_in[1],  (const float*)d_in[2],  (const float*)d_in[3],  (const float*)d_in[4],
        (const float*)d_in[5],  (const float*)d_in[6],  (const float*)d_in[7],  (const float*)d_in[8],
        (const float*)d_in[9],  (const float*)d_in[10], (const float*)d_in[11], (const float*)d_in[12],
        ws);

    for (int s = 0; s < Tt + 2; ++s)
        step_kernel<<<192, 256, 0, stream>>>(x, ws, s);

    fc_kernel<<<1, 256, 0, stream>>>(ws, (const float*)d_in[13], (const float*)d_in[14], (float*)d_out);
}